// Round 8
// baseline (590.473 us; speedup 1.0000x reference)
//
#include <hip/hip_runtime.h>
#include <stdint.h>

#define NB 4096
#define NT 200
#define NE 64
// attention: 4E=256 -> 64 -> 32 -> 1 ; final MLP: 272 -> 256 -> 128 -> 1
//
// ABI (proven R2-R10): identity order, fp32 floats, int32 ints, FP32 output.
//
// R21: R20 + waves_per_eu(4,4) (kill the AGPR churn for real).
//  - R20 post-mortem: 217us, VALUBusy 94%, VGPR=64. Allocator chose
//    64 arch + ~96 acc (= 160/wave, 3.2 waves/SIMD, occ 41%) -- every
//    acc access is an accvgpr mov: measured VALU-busy 204us vs ~94us of
//    real work (2.2x churn). Allocator maximizes occupancy given
//    min_waves, shunting live state to AGPRs.
//  - Now: waves_per_eu(4,4) pins occupancy at 4 waves/SIMD, budget
//    512/4 = 128 total/wave. Live set ~118 (kA+kB 64, h2 32, transients
//    ~16, misc) fits in ARCH regs -> no acc, no movs. Compiler can't
//    gain occupancy by shrinking arch, so it shouldn't try.
//  - Split dot accumulators (aA0/aA1) halve FMA chain depth to 16
//    (insurance at 4-wave residency).
//  - din_mlp: unchanged (MR=4); if attn drops below it, its counters
//    finally surface in the top-5.

// compile-time component access into a float4[] register array
#define C4(v, i) (((i)&3)==0 ? v[(i)>>2].x : ((i)&3)==1 ? v[(i)>>2].y : \
                  ((i)&3)==2 ? v[(i)>>2].z : v[(i)>>2].w)

// pair-swap (lane xor 1) on the VALU pipe: quad_perm [1,0,3,2] = 0xB1
__device__ __forceinline__ float dpp_xor1(float x)
{
    return __int_as_float(__builtin_amdgcn_update_dpp(
        0, __float_as_int(x), 0xB1, 0xF, 0xF, true));
}

// butterfly over the 32 same-half lanes (g = lane>>1), 32 elems -> elem g
#define BFH(S)                                                             \
    {                                                                      \
        const bool hi = (g & (S)) != 0;                                    \
        _Pragma("unroll")                                                  \
        for (int i = 0; i < (S); ++i) {                                    \
            const float snd = hi ? C4(kA, i) : C4(kA, i + (S));            \
            const float rec = __shfl_xor(snd, 2 * (S), 64);                \
            C4(kA, i) = (hi ? C4(kA, i + (S)) : C4(kA, i)) + rec;          \
        }                                                                  \
    }

struct __align__(16) SmemA {
    float weffT[64 * 72];   // [j][e], e padded 64->72 (288B rows, 16B-aligned)
    float w2[64 * 32];      // [j][o]
    float q[64];
    float biasj[64];
    float b2[32];
    float wo[32];
    float ip[4 * 64];       // bias partials, later interest partials
    float red_a[4];
    float red_b[4];
};                           // 28448 B

__global__ __launch_bounds__(256)
__attribute__((amdgpu_waves_per_eu(4, 4)))
void din_attn(const int* __restrict__ target_item,
              const int* __restrict__ history_items,
              const int* __restrict__ history_mask,
              const int* __restrict__ sparse_features,
              const float* __restrict__ dense_features,
              const float* __restrict__ item_table,
              const float* __restrict__ user_table,
              const float* __restrict__ ctx_table,
              const float* __restrict__ att_w1,
              const float* __restrict__ att_b1,
              const float* __restrict__ att_w2,
              const float* __restrict__ att_b2,
              const float* __restrict__ att_wo,
              const float* __restrict__ att_bo,
              float* __restrict__ mlp_in)   // [NB][272]
{
    __shared__ SmemA sm;

    const int b    = blockIdx.x;
    const int tid  = threadIdx.x;    // 0..255
    const int j    = tid & 63;       // lane in wave
    const int wv   = tid >> 6;       // 0..3
    const int half = tid & 1;        // 0: e[0,32), 1: e[32,64)
    const int g    = j >> 1;         // pair index in wave, 0..31
    const int p    = tid >> 1;       // pair index in block, 0..127
    const int tA   = p;              // < 200 always
    const int tB   = p + 128;
    const bool actB = (tB < NT);

    // ---- issue own half-key loads FIRST (registers; overlap staging) ----
    const int hrA = history_items[(size_t)b * NT + tA];
    const int hrB = history_items[(size_t)b * NT + (actB ? tB : 0)];
    float4 kA[8], kB[8];
    {
        const float4* rpA = (const float4*)(item_table + (size_t)hrA * NE) + half * 8;
        const float4* rpB = (const float4*)(item_table + (size_t)hrB * NE) + half * 8;
#pragma unroll
        for (int i = 0; i < 8; ++i) { kA[i] = rpA[i]; kB[i] = rpB[i]; }
    }

    // ---- stage small shared data ----------------------------------------
    if (tid < NE) sm.q[tid] = item_table[(size_t)target_item[b] * NE + tid];
    for (int i = tid; i < 512; i += 256)
        ((float4*)sm.w2)[i] = ((const float4*)att_w2)[i];
    if (tid < 32) { sm.b2[tid] = att_b2[tid]; sm.wo[tid] = att_wo[tid]; }
    const float bo = att_bo[0];
    __syncthreads();

    // ---- W_eff^T[j][e] + bias partials (thread = (wv, j), 16 e's) -------
    // attn_in = [k, q, k-q, k*q] @ w1 factorizes (q row-constant):
    // h1[j] = relu( sum_e k_e*(w1[e,j]+w1[128+e,j]+q_e*w1[192+e,j])
    //              + b1[j] + sum_e q_e*(w1[64+e,j]-w1[128+e,j]) )
    {
        float pb = 0.f;
        for (int e = wv; e < NE; e += 4) {
            const float qe = sm.q[e];
            const float A  = att_w1[(size_t)(e)       * NE + j];
            const float Bv = att_w1[(size_t)(64 + e)  * NE + j];
            const float C  = att_w1[(size_t)(128 + e) * NE + j];
            const float D  = att_w1[(size_t)(192 + e) * NE + j];
            sm.weffT[j * 72 + e] = A + C + qe * D;
            pb += qe * (Bv - C);
        }
        sm.ip[wv * 64 + j] = pb;
    }
    __syncthreads();
    if (tid < NE)
        sm.biasj[tid] = att_b1[tid] + sm.ip[tid] + sm.ip[64 + tid] +
                        sm.ip[128 + tid] + sm.ip[192 + tid];
    __syncthreads();

    // ---- main loop: each lane does its e-half of both t's ---------------
    float h2A[16], h2B[16];
#pragma unroll
    for (int o = 0; o < 16; ++o) { h2A[o] = 0.f; h2B[o] = 0.f; }

    for (int jj = 0; jj < 64; ++jj) {
        const float4* wrow =
            (const float4*)(sm.weffT + jj * 72 + (half << 5));   // own half
        float aA0 = 0.f, aA1 = 0.f, aB0 = 0.f, aB1 = 0.f;
#pragma unroll
        for (int gi = 0; gi < 8; gi += 2) {          // 2 float4 in flight
            const float4 w0 = wrow[gi + 0];
            const float4 w1 = wrow[gi + 1];
            aA0 += w0.x * kA[gi + 0].x; aB0 += w0.x * kB[gi + 0].x;
            aA0 += w0.y * kA[gi + 0].y; aB0 += w0.y * kB[gi + 0].y;
            aA0 += w0.z * kA[gi + 0].z; aB0 += w0.z * kB[gi + 0].z;
            aA0 += w0.w * kA[gi + 0].w; aB0 += w0.w * kB[gi + 0].w;
            aA1 += w1.x * kA[gi + 1].x; aB1 += w1.x * kB[gi + 1].x;
            aA1 += w1.y * kA[gi + 1].y; aB1 += w1.y * kB[gi + 1].y;
            aA1 += w1.z * kA[gi + 1].z; aB1 += w1.z * kB[gi + 1].z;
            aA1 += w1.w * kA[gi + 1].w; aB1 += w1.w * kB[gi + 1].w;
        }
        float aA = aA0 + aA1;
        float aB = aB0 + aB1;
        // combine halves within the pair on the VALU pipe (quad-perm DPP)
        aA += dpp_xor1(aA);
        aB += dpp_xor1(aB);
        const float bias = sm.biasj[jj];
        const float h1A = fmaxf(aA + bias, 0.f);
        const float h1B = fmaxf(aB + bias, 0.f);

        const float4* w2row =
            (const float4*)(sm.w2 + jj * 32) + (half << 2);      // own half
#pragma unroll
        for (int o4 = 0; o4 < 4; ++o4) {             // 1 float4 in flight
            const float4 ww = w2row[o4];
            h2A[4 * o4 + 0] += h1A * ww.x;  h2B[4 * o4 + 0] += h1B * ww.x;
            h2A[4 * o4 + 1] += h1A * ww.y;  h2B[4 * o4 + 1] += h1B * ww.y;
            h2A[4 * o4 + 2] += h1A * ww.z;  h2B[4 * o4 + 2] += h1B * ww.z;
            h2A[4 * o4 + 3] += h1A * ww.w;  h2B[4 * o4 + 3] += h1B * ww.w;
        }
    }

    // ---- L3 scores (each lane: own 16-o half, then pair-combine) --------
    float sA = 0.f, sB = 0.f;
#pragma unroll
    for (int o = 0; o < 16; ++o) {
        const float bb  = sm.b2[half * 16 + o];
        const float wwo = sm.wo[half * 16 + o];
        sA += fmaxf(h2A[o] + bb, 0.f) * wwo;
        sB += fmaxf(h2B[o] + bb, 0.f) * wwo;
    }
    sA += dpp_xor1(sA);
    sB += dpp_xor1(sB);
    const float scrA = sA + bo;
    const float scrB = sB + bo;
    const int mkA = history_mask[(size_t)b * NT + tA];
    const int mkB = actB ? history_mask[(size_t)b * NT + tB] : 0;
    const float vA = (mkA != 0) ? scrA : -1e9f;
    const float vB = actB ? ((mkB != 0) ? scrB : -1e9f) : -INFINITY;
    // even lane represents tA, odd lane tB -> each t counted exactly once
    const float v = half ? vB : vA;

    // ---- softmax over 256 slots (4-wave reduce) -------------------------
    float m = v;
#pragma unroll
    for (int s = 32; s; s >>= 1) m = fmaxf(m, __shfl_xor(m, s));
    if (j == 0) sm.red_a[wv] = m;
    __syncthreads();
    const float mx = fmaxf(fmaxf(sm.red_a[0], sm.red_a[1]),
                           fmaxf(sm.red_a[2], sm.red_a[3]));
    const float ex = __expf(v - mx);   // -inf -> 0
    float ssum = ex;
#pragma unroll
    for (int s = 32; s; s >>= 1) ssum += __shfl_xor(ssum, s);
    if (j == 0) sm.red_b[wv] = ssum;
    __syncthreads();
    const float total = sm.red_b[0] + sm.red_b[1] + sm.red_b[2] + sm.red_b[3];
    const float w = ex / total;
    const float wOther = dpp_xor1(w);
    const float wA = half ? wOther : w;
    const float wB = half ? w : wOther;

    // ---- interest: own e-half of both t's, butterfly over 32 pairs ------
#pragma unroll
    for (int i = 0; i < 32; ++i)
        C4(kA, i) = C4(kA, i) * wA + C4(kB, i) * wB;
    BFH(16)
    BFH(8)
    BFH(4)
    BFH(2)
    BFH(1)
    // lane now holds this wave's partial interest for e = half*32 + g
    sm.ip[wv * 64 + half * 32 + g] = kA[0].x;
    __syncthreads();

    // ---- assemble mlp_in row [user, ctx, q, interest, dense] ------------
    float* row = mlp_in + (size_t)b * 272;
    if (tid < NE) {
        const float inter = sm.ip[tid] + sm.ip[64 + tid] +
                            sm.ip[128 + tid] + sm.ip[192 + tid];
        row[0 + tid]   = user_table[(size_t)sparse_features[b * 2 + 0] * NE + tid];
        row[64 + tid]  = ctx_table[(size_t)sparse_features[b * 2 + 1] * NE + tid];
        row[128 + tid] = sm.q[tid];
        row[192 + tid] = inter;
    } else if (tid >= 64 && tid < 80) {
        row[256 + (tid - 64)] = dense_features[(size_t)b * 16 + (tid - 64)];
    }
}

// ---------------------------------------------------------------------------
// Kernel 2: final MLP 272 -> 256 -> 128 -> 1, 4 rows/block (grid 1024,
// 4 blocks/CU) with transposed LDS activations (broadcast b128 reads) and
// unroll-8 load pipelining.
// ---------------------------------------------------------------------------
#define MR 4
__global__ __launch_bounds__(256)
void din_mlp(const float* __restrict__ mlp_in,
             const float* __restrict__ w1,
             const float* __restrict__ b1,
             const float* __restrict__ w2,
             const float* __restrict__ b2,
             const float* __restrict__ ow,
             const float* __restrict__ ob,
             float* __restrict__ out)
{
    __shared__ float inT[272 * MR];     // [k][r]
    __shared__ float h1T[256 * MR];     // [k][r]
    __shared__ float p2[2 * MR * 128];
    __shared__ float h2_lds[MR * 128];

    const int b0  = blockIdx.x * MR;
    const int tid = threadIdx.x;

    // stage transposed: coalesced global read, scattered LDS write
    for (int i = tid; i < MR * 272; i += 256) {
        const int r = i / 272, k = i - 272 * r;
        inT[k * MR + r] = mlp_in[(size_t)b0 * 272 + i];
    }
    __syncthreads();

    // layer 1: 272 -> 256 (thread = col, MR rows via 1 b128 broadcast/k)
    {
        const float bias = b1[tid];
        float a0 = bias, a1 = bias, a2 = bias, a3 = bias;
        const float4* iT = (const float4*)inT;
#pragma unroll 8
        for (int k = 0; k < 272; ++k) {
            const float wv = w1[(size_t)k * 256 + tid];
            const float4 iv = iT[k];
            a0 += iv.x * wv; a1 += iv.y * wv;
            a2 += iv.z * wv; a3 += iv.w * wv;
        }
        float4 o;
        o.x = fmaxf(a0, 0.f); o.y = fmaxf(a1, 0.f);
        o.z = fmaxf(a2, 0.f); o.w = fmaxf(a3, 0.f);
        ((float4*)h1T)[tid] = o;        // h1T[k=tid][r] contiguous
    }
    __syncthreads();

    // layer 2: 256 -> 128, split-K over two half-blocks
    {
        const int o = tid & 127, half = tid >> 7;
        float c0 = 0.f, c1 = 0.f, c2 = 0.f, c3 = 0.f;
        const float4* hT = (const float4*)h1T;
#pragma unroll 8
        for (int kk = 0; kk < 128; ++kk) {
            const int k = half * 128 + kk;
            const float wv = w2[(size_t)k * 128 + o];
            const float4 hv = hT[k];
            c0 += hv.x * wv; c1 += hv.y * wv;
            c2 += hv.z * wv; c3 += hv.w * wv;
        }
        p2[(half * MR + 0) * 128 + o] = c0;
        p2[(half * MR + 1) * 128 + o] = c1;
        p2[(half * MR + 2) * 128 + o] = c2;
        p2[(half * MR + 3) * 128 + o] = c3;
    }
    __syncthreads();
    if (tid < 128) {
        const float bias = b2[tid];
#pragma unroll
        for (int r = 0; r < MR; ++r)
            h2_lds[r * 128 + tid] =
                fmaxf(p2[r * 128 + tid] + p2[(MR + r) * 128 + tid] + bias, 0.f);
    }
    __syncthreads();

    // layer 3: 128 -> 1 (16 lanes per row)
    if (tid < 16 * MR) {
        const int r = tid >> 4, l = tid & 15;
        float a = 0.f;
#pragma unroll
        for (int kk = 0; kk < 8; ++kk) {
            const int k = l * 8 + kk;
            a += h2_lds[r * 128 + k] * ow[k];
        }
        a += __shfl_xor(a, 8, 16);
        a += __shfl_xor(a, 4, 16);
        a += __shfl_xor(a, 2, 16);
        a += __shfl_xor(a, 1, 16);
        if (l == 0) out[b0 + r] = a + ob[0];
    }
}

// ---------------------------------------------------------------------------
extern "C" void kernel_launch(void* const* d_in, const int* in_sizes, int n_in,
                              void* d_out, int out_size, void* d_ws, size_t ws_size,
                              hipStream_t stream)
{
    float* mlp_in = (float*)d_ws;   // 4096*272*4 = 4.46 MB

    din_attn<<<NB, 256, 0, stream>>>(
        (const int*)d_in[0],      // target_item
        (const int*)d_in[1],      // history_items
        (const int*)d_in[2],      // history_mask
        (const int*)d_in[3],      // sparse_features
        (const float*)d_in[4],    // dense_features
        (const float*)d_in[5],    // item_table
        (const float*)d_in[6],    // user_table
        (const float*)d_in[7],    // ctx_table
        (const float*)d_in[8],  (const float*)d_in[9],   // att_w1, att_b1
        (const float*)d_in[10], (const float*)d_in[11],  // att_w2, att_b2
        (const float*)d_in[12], (const float*)d_in[13],  // att_wo, att_bo
        mlp_in);

    din_mlp<<<NB / MR, 256, 0, stream>>>(
        mlp_in,
        (const float*)d_in[14], (const float*)d_in[15],  // mlp_w1, mlp_b1
        (const float*)d_in[16], (const float*)d_in[17],  // mlp_w2, mlp_b2
        (const float*)d_in[18], (const float*)d_in[19],  // out_w, out_b
        (float*)d_out);
}

// Round 9
// 381.761 us; speedup vs baseline: 1.5467x; 1.5467x over previous
//
#include <hip/hip_runtime.h>
#include <stdint.h>

#define NB 4096
#define NT 200
#define NE 64
// attention: 4E=256 -> 64 -> 32 -> 1 ; final MLP: 272 -> 256 -> 128 -> 1
//
// ABI (proven R2-R10): identity order, fp32 floats, int32 ints, FP32 output.
//
// R22: quad-split (4 t per lane-quad) + waves_per_eu(2,2).
//  - R20 (best, 217us): VALU 94% busy (94us real + 2.2x AGPR churn),
//    LDS ~49K instr/CU ~= 184us. Both pipes near-saturated.
//  - R21 (4,4): budget 128 TOTAL/wave, live ~130 -> hot-loop scratch
//    spill (WRITE 270MB), 505us. Allocator targets the MAX of the
//    waves_per_eu range; (2,4) chased 4 waves by shrinking arch to 64.
//  - Now: (2,2) pins 2 waves/SIMD -> 256 total budget, no incentive to
//    shrink arch below live (~125) -> all-arch, no churn, no spill.
//  - Quad-split: lane quad owns tA=p,tB=p+64,tC=p+128,tD=p+192; each
//    lane keeps the e-quarter (16 floats) of all 4 keys. Per jj: 4 b128
//    (weff quarter) + 2 b128 (w2 quarter) + 1 b32 (bias) = 7 LDS
//    instr/jj/wave (vs 12), reused by 4 t's -> LDS ~110us. Quad combines
//    on VALU pipe via quad-perm DPP (xor1/xor2, bcast0..3).
//    weff quarter addrs = 2 distinct/bank-group = free (m136).
//  - Register state invariant vs R20: keys 64 + h2 32 = 96 live.
//  - din_mlp: unchanged (MR=4, transposed LDS, unroll-8).

// compile-time component access into a float4[] register array
#define C4(v, i) (((i)&3)==0 ? v[(i)>>2].x : ((i)&3)==1 ? v[(i)>>2].y : \
                  ((i)&3)==2 ? v[(i)>>2].z : v[(i)>>2].w)

// quad-perm DPP helpers (VALU pipe, no LDS)
__device__ __forceinline__ float dpp_xor1(float x)   // [1,0,3,2]
{
    return __int_as_float(__builtin_amdgcn_update_dpp(
        0, __float_as_int(x), 0xB1, 0xF, 0xF, true));
}
__device__ __forceinline__ float dpp_xor2(float x)   // [2,3,0,1]
{
    return __int_as_float(__builtin_amdgcn_update_dpp(
        0, __float_as_int(x), 0x4E, 0xF, 0xF, true));
}
__device__ __forceinline__ float dpp_b0(float x)     // [0,0,0,0]
{
    return __int_as_float(__builtin_amdgcn_update_dpp(
        0, __float_as_int(x), 0x00, 0xF, 0xF, true));
}
__device__ __forceinline__ float dpp_b1(float x)     // [1,1,1,1]
{
    return __int_as_float(__builtin_amdgcn_update_dpp(
        0, __float_as_int(x), 0x55, 0xF, 0xF, true));
}
__device__ __forceinline__ float dpp_b2(float x)     // [2,2,2,2]
{
    return __int_as_float(__builtin_amdgcn_update_dpp(
        0, __float_as_int(x), 0xAA, 0xF, 0xF, true));
}
__device__ __forceinline__ float dpp_b3(float x)     // [3,3,3,3]
{
    return __int_as_float(__builtin_amdgcn_update_dpp(
        0, __float_as_int(x), 0xFF, 0xF, 0xF, true));
}

// butterfly over the 16 same-quarter groups (g = lane>>2), 16 elems -> elem g
#define BFQ(S)                                                             \
    {                                                                      \
        const bool hi = (g & (S)) != 0;                                    \
        _Pragma("unroll")                                                  \
        for (int i = 0; i < (S); ++i) {                                    \
            const float snd = hi ? C4(kA, i) : C4(kA, i + (S));            \
            const float rec = __shfl_xor(snd, 4 * (S), 64);                \
            C4(kA, i) = (hi ? C4(kA, i + (S)) : C4(kA, i)) + rec;          \
        }                                                                  \
    }

struct __align__(16) SmemA {
    float weffT[64 * 72];   // [j][e], e padded 64->72 (288B rows, 16B-aligned)
    float w2[64 * 32];      // [j][o]
    float q[64];
    float biasj[64];
    float b2[32];
    float wo[32];
    float ip[4 * 64];       // bias partials, later interest partials
    float red_a[4];
    float red_b[4];
};                           // 28448 B

__global__ __launch_bounds__(256)
__attribute__((amdgpu_waves_per_eu(2, 2)))
void din_attn(const int* __restrict__ target_item,
              const int* __restrict__ history_items,
              const int* __restrict__ history_mask,
              const int* __restrict__ sparse_features,
              const float* __restrict__ dense_features,
              const float* __restrict__ item_table,
              const float* __restrict__ user_table,
              const float* __restrict__ ctx_table,
              const float* __restrict__ att_w1,
              const float* __restrict__ att_b1,
              const float* __restrict__ att_w2,
              const float* __restrict__ att_b2,
              const float* __restrict__ att_wo,
              const float* __restrict__ att_bo,
              float* __restrict__ mlp_in)   // [NB][272]
{
    __shared__ SmemA sm;

    const int b    = blockIdx.x;
    const int tid  = threadIdx.x;    // 0..255
    const int j    = tid & 63;       // lane in wave
    const int wv   = tid >> 6;       // 0..3
    const int quarter = tid & 3;     // e-quarter: [16q, 16q+16)
    const int g    = (tid >> 2) & 15;// group within wave, 0..15
    const int p    = tid >> 2;       // quad index in block, 0..63
    const int tA   = p;              // < 200 always
    const int tB   = p + 64;         // < 200 always
    const int tC   = p + 128;        // < 200 always
    const int tD   = p + 192;        // active iff < 200 (p < 8)
    const bool actD = (tD < NT);

    // ---- issue own quarter-key loads FIRST (registers; overlap staging) -
    const int hrA = history_items[(size_t)b * NT + tA];
    const int hrB = history_items[(size_t)b * NT + tB];
    const int hrC = history_items[(size_t)b * NT + tC];
    const int hrD = history_items[(size_t)b * NT + (actD ? tD : 0)];
    float4 kA[4], kB[4], kC[4], kD[4];
    {
        const float4* rpA = (const float4*)(item_table + (size_t)hrA * NE) + quarter * 4;
        const float4* rpB = (const float4*)(item_table + (size_t)hrB * NE) + quarter * 4;
        const float4* rpC = (const float4*)(item_table + (size_t)hrC * NE) + quarter * 4;
        const float4* rpD = (const float4*)(item_table + (size_t)hrD * NE) + quarter * 4;
#pragma unroll
        for (int i = 0; i < 4; ++i) {
            kA[i] = rpA[i]; kB[i] = rpB[i]; kC[i] = rpC[i]; kD[i] = rpD[i];
        }
    }

    // ---- stage small shared data ----------------------------------------
    if (tid < NE) sm.q[tid] = item_table[(size_t)target_item[b] * NE + tid];
    for (int i = tid; i < 512; i += 256)
        ((float4*)sm.w2)[i] = ((const float4*)att_w2)[i];
    if (tid < 32) { sm.b2[tid] = att_b2[tid]; sm.wo[tid] = att_wo[tid]; }
    const float bo = att_bo[0];
    __syncthreads();

    // ---- W_eff^T[j][e] + bias partials (thread = (wv, j), 16 e's) -------
    // attn_in = [k, q, k-q, k*q] @ w1 factorizes (q row-constant):
    // h1[j] = relu( sum_e k_e*(w1[e,j]+w1[128+e,j]+q_e*w1[192+e,j])
    //              + b1[j] + sum_e q_e*(w1[64+e,j]-w1[128+e,j]) )
    {
        float pb = 0.f;
        for (int e = wv; e < NE; e += 4) {
            const float qe = sm.q[e];
            const float A  = att_w1[(size_t)(e)       * NE + j];
            const float Bv = att_w1[(size_t)(64 + e)  * NE + j];
            const float C  = att_w1[(size_t)(128 + e) * NE + j];
            const float D  = att_w1[(size_t)(192 + e) * NE + j];
            sm.weffT[j * 72 + e] = A + C + qe * D;
            pb += qe * (Bv - C);
        }
        sm.ip[wv * 64 + j] = pb;
    }
    __syncthreads();
    if (tid < NE)
        sm.biasj[tid] = att_b1[tid] + sm.ip[tid] + sm.ip[64 + tid] +
                        sm.ip[128 + tid] + sm.ip[192 + tid];
    __syncthreads();

    // ---- main loop: lane does its e-quarter of FOUR t's -----------------
    float h2A[8], h2B[8], h2C[8], h2D[8];
#pragma unroll
    for (int o = 0; o < 8; ++o) { h2A[o] = 0.f; h2B[o] = 0.f; h2C[o] = 0.f; h2D[o] = 0.f; }

    for (int jj = 0; jj < 64; ++jj) {
        const float4* wrow =
            (const float4*)(sm.weffT + jj * 72) + quarter * 4;   // own quarter
        float aA = 0.f, aB = 0.f, aC = 0.f, aD = 0.f;
#pragma unroll
        for (int i = 0; i < 4; ++i) {
            const float4 w = wrow[i];
            aA += w.x * kA[i].x; aB += w.x * kB[i].x;
            aC += w.x * kC[i].x; aD += w.x * kD[i].x;
            aA += w.y * kA[i].y; aB += w.y * kB[i].y;
            aC += w.y * kC[i].y; aD += w.y * kD[i].y;
            aA += w.z * kA[i].z; aB += w.z * kB[i].z;
            aC += w.z * kC[i].z; aD += w.z * kD[i].z;
            aA += w.w * kA[i].w; aB += w.w * kB[i].w;
            aC += w.w * kC[i].w; aD += w.w * kD[i].w;
        }
        // combine quarters within the quad (quad-perm DPP, VALU pipe)
        aA += dpp_xor1(aA); aA += dpp_xor2(aA);
        aB += dpp_xor1(aB); aB += dpp_xor2(aB);
        aC += dpp_xor1(aC); aC += dpp_xor2(aC);
        aD += dpp_xor1(aD); aD += dpp_xor2(aD);
        const float bias = sm.biasj[jj];
        const float h1A = fmaxf(aA + bias, 0.f);
        const float h1B = fmaxf(aB + bias, 0.f);
        const float h1C = fmaxf(aC + bias, 0.f);
        const float h1D = fmaxf(aD + bias, 0.f);

        const float4* w2q =
            (const float4*)(sm.w2 + jj * 32) + quarter * 2;      // own quarter
        const float4 u0 = w2q[0];
        const float4 u1 = w2q[1];
        h2A[0] += h1A * u0.x; h2B[0] += h1B * u0.x; h2C[0] += h1C * u0.x; h2D[0] += h1D * u0.x;
        h2A[1] += h1A * u0.y; h2B[1] += h1B * u0.y; h2C[1] += h1C * u0.y; h2D[1] += h1D * u0.y;
        h2A[2] += h1A * u0.z; h2B[2] += h1B * u0.z; h2C[2] += h1C * u0.z; h2D[2] += h1D * u0.z;
        h2A[3] += h1A * u0.w; h2B[3] += h1B * u0.w; h2C[3] += h1C * u0.w; h2D[3] += h1D * u0.w;
        h2A[4] += h1A * u1.x; h2B[4] += h1B * u1.x; h2C[4] += h1C * u1.x; h2D[4] += h1D * u1.x;
        h2A[5] += h1A * u1.y; h2B[5] += h1B * u1.y; h2C[5] += h1C * u1.y; h2D[5] += h1D * u1.y;
        h2A[6] += h1A * u1.z; h2B[6] += h1B * u1.z; h2C[6] += h1C * u1.z; h2D[6] += h1D * u1.z;
        h2A[7] += h1A * u1.w; h2B[7] += h1B * u1.w; h2C[7] += h1C * u1.w; h2D[7] += h1D * u1.w;
    }

    // ---- L3 scores (own 8-o quarter, then quad-combine) -----------------
    float sA = 0.f, sB = 0.f, sC = 0.f, sD = 0.f;
#pragma unroll
    for (int o = 0; o < 8; ++o) {
        const float bb  = sm.b2[quarter * 8 + o];
        const float wwo = sm.wo[quarter * 8 + o];
        sA += fmaxf(h2A[o] + bb, 0.f) * wwo;
        sB += fmaxf(h2B[o] + bb, 0.f) * wwo;
        sC += fmaxf(h2C[o] + bb, 0.f) * wwo;
        sD += fmaxf(h2D[o] + bb, 0.f) * wwo;
    }
    sA += dpp_xor1(sA); sA += dpp_xor2(sA);
    sB += dpp_xor1(sB); sB += dpp_xor2(sB);
    sC += dpp_xor1(sC); sC += dpp_xor2(sC);
    sD += dpp_xor1(sD); sD += dpp_xor2(sD);
    const float scrA = sA + bo;
    const float scrB = sB + bo;
    const float scrC = sC + bo;
    const float scrD = sD + bo;
    const int mkA = history_mask[(size_t)b * NT + tA];
    const int mkB = history_mask[(size_t)b * NT + tB];
    const int mkC = history_mask[(size_t)b * NT + tC];
    const int mkD = actD ? history_mask[(size_t)b * NT + tD] : 0;
    const float vA = (mkA != 0) ? scrA : -1e9f;
    const float vB = (mkB != 0) ? scrB : -1e9f;
    const float vC = (mkC != 0) ? scrC : -1e9f;
    const float vD = actD ? ((mkD != 0) ? scrD : -1e9f) : -INFINITY;
    // lane's quarter selects which t it represents -> 256 slots, each once
    const float v = (quarter == 0) ? vA : (quarter == 1) ? vB
                  : (quarter == 2) ? vC : vD;

    // ---- softmax over 256 slots (4-wave reduce) -------------------------
    float m = v;
#pragma unroll
    for (int s = 32; s; s >>= 1) m = fmaxf(m, __shfl_xor(m, s));
    if (j == 0) sm.red_a[wv] = m;
    __syncthreads();
    const float mx = fmaxf(fmaxf(sm.red_a[0], sm.red_a[1]),
                           fmaxf(sm.red_a[2], sm.red_a[3]));
    const float ex = __expf(v - mx);   // -inf -> 0
    float ssum = ex;
#pragma unroll
    for (int s = 32; s; s >>= 1) ssum += __shfl_xor(ssum, s);
    if (j == 0) sm.red_b[wv] = ssum;
    __syncthreads();
    const float total = sm.red_b[0] + sm.red_b[1] + sm.red_b[2] + sm.red_b[3];
    const float w = ex / total;
    // redistribute all four t-weights to every lane of the quad (DPP bcast)
    const float wA = dpp_b0(w);
    const float wB = dpp_b1(w);
    const float wC = dpp_b2(w);
    const float wD = dpp_b3(w);

    // ---- interest: own e-quarter of 4 t's, butterfly over 16 groups -----
#pragma unroll
    for (int i = 0; i < 16; ++i)
        C4(kA, i) = C4(kA, i) * wA + C4(kB, i) * wB +
                    C4(kC, i) * wC + C4(kD, i) * wD;
    BFQ(8)
    BFQ(4)
    BFQ(2)
    BFQ(1)
    // lane now holds this wave's partial interest for e = quarter*16 + g
    sm.ip[wv * 64 + quarter * 16 + g] = kA[0].x;
    __syncthreads();

    // ---- assemble mlp_in row [user, ctx, q, interest, dense] ------------
    float* row = mlp_in + (size_t)b * 272;
    if (tid < NE) {
        const float inter = sm.ip[tid] + sm.ip[64 + tid] +
                            sm.ip[128 + tid] + sm.ip[192 + tid];
        row[0 + tid]   = user_table[(size_t)sparse_features[b * 2 + 0] * NE + tid];
        row[64 + tid]  = ctx_table[(size_t)sparse_features[b * 2 + 1] * NE + tid];
        row[128 + tid] = sm.q[tid];
        row[192 + tid] = inter;
    } else if (tid >= 64 && tid < 80) {
        row[256 + (tid - 64)] = dense_features[(size_t)b * 16 + (tid - 64)];
    }
}

// ---------------------------------------------------------------------------
// Kernel 2: final MLP 272 -> 256 -> 128 -> 1, 4 rows/block (grid 1024,
// 4 blocks/CU) with transposed LDS activations (broadcast b128 reads) and
// unroll-8 load pipelining.
// ---------------------------------------------------------------------------
#define MR 4
__global__ __launch_bounds__(256)
void din_mlp(const float* __restrict__ mlp_in,
             const float* __restrict__ w1,
             const float* __restrict__ b1,
             const float* __restrict__ w2,
             const float* __restrict__ b2,
             const float* __restrict__ ow,
             const float* __restrict__ ob,
             float* __restrict__ out)
{
    __shared__ float inT[272 * MR];     // [k][r]
    __shared__ float h1T[256 * MR];     // [k][r]
    __shared__ float p2[2 * MR * 128];
    __shared__ float h2_lds[MR * 128];

    const int b0  = blockIdx.x * MR;
    const int tid = threadIdx.x;

    // stage transposed: coalesced global read, scattered LDS write
    for (int i = tid; i < MR * 272; i += 256) {
        const int r = i / 272, k = i - 272 * r;
        inT[k * MR + r] = mlp_in[(size_t)b0 * 272 + i];
    }
    __syncthreads();

    // layer 1: 272 -> 256 (thread = col, MR rows via 1 b128 broadcast/k)
    {
        const float bias = b1[tid];
        float a0 = bias, a1 = bias, a2 = bias, a3 = bias;
        const float4* iT = (const float4*)inT;
#pragma unroll 8
        for (int k = 0; k < 272; ++k) {
            const float wv = w1[(size_t)k * 256 + tid];
            const float4 iv = iT[k];
            a0 += iv.x * wv; a1 += iv.y * wv;
            a2 += iv.z * wv; a3 += iv.w * wv;
        }
        float4 o;
        o.x = fmaxf(a0, 0.f); o.y = fmaxf(a1, 0.f);
        o.z = fmaxf(a2, 0.f); o.w = fmaxf(a3, 0.f);
        ((float4*)h1T)[tid] = o;        // h1T[k=tid][r] contiguous
    }
    __syncthreads();

    // layer 2: 256 -> 128, split-K over two half-blocks
    {
        const int o = tid & 127, half = tid >> 7;
        float c0 = 0.f, c1 = 0.f, c2 = 0.f, c3 = 0.f;
        const float4* hT = (const float4*)h1T;
#pragma unroll 8
        for (int kk = 0; kk < 128; ++kk) {
            const int k = half * 128 + kk;
            const float wv = w2[(size_t)k * 128 + o];
            const float4 hv = hT[k];
            c0 += hv.x * wv; c1 += hv.y * wv;
            c2 += hv.z * wv; c3 += hv.w * wv;
        }
        p2[(half * MR + 0) * 128 + o] = c0;
        p2[(half * MR + 1) * 128 + o] = c1;
        p2[(half * MR + 2) * 128 + o] = c2;
        p2[(half * MR + 3) * 128 + o] = c3;
    }
    __syncthreads();
    if (tid < 128) {
        const float bias = b2[tid];
#pragma unroll
        for (int r = 0; r < MR; ++r)
            h2_lds[r * 128 + tid] =
                fmaxf(p2[r * 128 + tid] + p2[(MR + r) * 128 + tid] + bias, 0.f);
    }
    __syncthreads();

    // layer 3: 128 -> 1 (16 lanes per row)
    if (tid < 16 * MR) {
        const int r = tid >> 4, l = tid & 15;
        float a = 0.f;
#pragma unroll
        for (int kk = 0; kk < 8; ++kk) {
            const int k = l * 8 + kk;
            a += h2_lds[r * 128 + k] * ow[k];
        }
        a += __shfl_xor(a, 8, 16);
        a += __shfl_xor(a, 4, 16);
        a += __shfl_xor(a, 2, 16);
        a += __shfl_xor(a, 1, 16);
        if (l == 0) out[b0 + r] = a + ob[0];
    }
}

// ---------------------------------------------------------------------------
extern "C" void kernel_launch(void* const* d_in, const int* in_sizes, int n_in,
                              void* d_out, int out_size, void* d_ws, size_t ws_size,
                              hipStream_t stream)
{
    float* mlp_in = (float*)d_ws;   // 4096*272*4 = 4.46 MB

    din_attn<<<NB, 256, 0, stream>>>(
        (const int*)d_in[0],      // target_item
        (const int*)d_in[1],      // history_items
        (const int*)d_in[2],      // history_mask
        (const int*)d_in[3],      // sparse_features
        (const float*)d_in[4],    // dense_features
        (const float*)d_in[5],    // item_table
        (const float*)d_in[6],    // user_table
        (const float*)d_in[7],    // ctx_table
        (const float*)d_in[8],  (const float*)d_in[9],   // att_w1, att_b1
        (const float*)d_in[10], (const float*)d_in[11],  // att_w2, att_b2
        (const float*)d_in[12], (const float*)d_in[13],  // att_wo, att_bo
        mlp_in);

    din_mlp<<<NB / MR, 256, 0, stream>>>(
        mlp_in,
        (const float*)d_in[14], (const float*)d_in[15],  // mlp_w1, mlp_b1
        (const float*)d_in[16], (const float*)d_in[17],  // mlp_w2, mlp_b2
        (const float*)d_in[18], (const float*)d_in[19],  // out_w, out_b
        (float*)d_out);
}

// Round 10
// 349.859 us; speedup vs baseline: 1.6877x; 1.0912x over previous
//
#include <hip/hip_runtime.h>
#include <stdint.h>

#define NB 4096
#define NT 200
#define NE 64
// attention: 4E=256 -> 64 -> 32 -> 1 ; final MLP: 272 -> 256 -> 128 -> 1
//
// ABI (proven R2-R10): identity order, fp32 floats, int32 ints, FP32 output.
//
// R23: quad-split + __launch_bounds__(256,2) (the one attr that grants
//      enough ARCH VGPRs).
//  - R22 post-mortem: quad-split LDS cut is real (7 instr/jj/wave) but
//    (2,2) pinned 2 waves/SIMD (no TLP) AND still granted only 88 arch
//    < 96 hot -> churn persisted: 280us, worse than R20's 217.
//  - Register ledger across R13-R22: hot state (keys 64 + h2 32 = 96) is
//    structural for 64-t/wave coverage. Only __launch_bounds__(256,2)
//    ever granted >=120 arch (R14). Quad live set ~116 <= 120 -> fits
//    all-arch, and 120 total <= 128 -> HW can run 4 waves/SIMD.
//  - Model: real VALU ~102us, LDS ~28.7K instr/CU ~110us, overlapped at
//    3-4 waves/SIMD -> ~140-180us. Signature: VGPR_Count ~116-120.
//  - din_mlp: unchanged (MR=4, transposed LDS, unroll-8).

// compile-time component access into a float4[] register array
#define C4(v, i) (((i)&3)==0 ? v[(i)>>2].x : ((i)&3)==1 ? v[(i)>>2].y : \
                  ((i)&3)==2 ? v[(i)>>2].z : v[(i)>>2].w)

// quad-perm DPP helpers (VALU pipe, no LDS)
__device__ __forceinline__ float dpp_xor1(float x)   // [1,0,3,2]
{
    return __int_as_float(__builtin_amdgcn_update_dpp(
        0, __float_as_int(x), 0xB1, 0xF, 0xF, true));
}
__device__ __forceinline__ float dpp_xor2(float x)   // [2,3,0,1]
{
    return __int_as_float(__builtin_amdgcn_update_dpp(
        0, __float_as_int(x), 0x4E, 0xF, 0xF, true));
}
__device__ __forceinline__ float dpp_b0(float x)     // [0,0,0,0]
{
    return __int_as_float(__builtin_amdgcn_update_dpp(
        0, __float_as_int(x), 0x00, 0xF, 0xF, true));
}
__device__ __forceinline__ float dpp_b1(float x)     // [1,1,1,1]
{
    return __int_as_float(__builtin_amdgcn_update_dpp(
        0, __float_as_int(x), 0x55, 0xF, 0xF, true));
}
__device__ __forceinline__ float dpp_b2(float x)     // [2,2,2,2]
{
    return __int_as_float(__builtin_amdgcn_update_dpp(
        0, __float_as_int(x), 0xAA, 0xF, 0xF, true));
}
__device__ __forceinline__ float dpp_b3(float x)     // [3,3,3,3]
{
    return __int_as_float(__builtin_amdgcn_update_dpp(
        0, __float_as_int(x), 0xFF, 0xF, 0xF, true));
}

// butterfly over the 16 same-quarter groups (g = lane>>2), 16 elems -> elem g
#define BFQ(S)                                                             \
    {                                                                      \
        const bool hi = (g & (S)) != 0;                                    \
        _Pragma("unroll")                                                  \
        for (int i = 0; i < (S); ++i) {                                    \
            const float snd = hi ? C4(kA, i) : C4(kA, i + (S));            \
            const float rec = __shfl_xor(snd, 4 * (S), 64);                \
            C4(kA, i) = (hi ? C4(kA, i + (S)) : C4(kA, i)) + rec;          \
        }                                                                  \
    }

struct __align__(16) SmemA {
    float weffT[64 * 72];   // [j][e], e padded 64->72 (288B rows, 16B-aligned)
    float w2[64 * 32];      // [j][o]
    float q[64];
    float biasj[64];
    float b2[32];
    float wo[32];
    float ip[4 * 64];       // bias partials, later interest partials
    float red_a[4];
    float red_b[4];
};                           // 28448 B

__global__ __launch_bounds__(256, 2)
void din_attn(const int* __restrict__ target_item,
              const int* __restrict__ history_items,
              const int* __restrict__ history_mask,
              const int* __restrict__ sparse_features,
              const float* __restrict__ dense_features,
              const float* __restrict__ item_table,
              const float* __restrict__ user_table,
              const float* __restrict__ ctx_table,
              const float* __restrict__ att_w1,
              const float* __restrict__ att_b1,
              const float* __restrict__ att_w2,
              const float* __restrict__ att_b2,
              const float* __restrict__ att_wo,
              const float* __restrict__ att_bo,
              float* __restrict__ mlp_in)   // [NB][272]
{
    __shared__ SmemA sm;

    const int b    = blockIdx.x;
    const int tid  = threadIdx.x;    // 0..255
    const int j    = tid & 63;       // lane in wave
    const int wv   = tid >> 6;       // 0..3
    const int quarter = tid & 3;     // e-quarter: [16q, 16q+16)
    const int g    = (tid >> 2) & 15;// group within wave, 0..15
    const int p    = tid >> 2;       // quad index in block, 0..63
    const int tA   = p;              // < 200 always
    const int tB   = p + 64;         // < 200 always
    const int tC   = p + 128;        // < 200 always
    const int tD   = p + 192;        // active iff < 200 (p < 8)
    const bool actD = (tD < NT);

    // ---- issue own quarter-key loads FIRST (registers; overlap staging) -
    const int hrA = history_items[(size_t)b * NT + tA];
    const int hrB = history_items[(size_t)b * NT + tB];
    const int hrC = history_items[(size_t)b * NT + tC];
    const int hrD = history_items[(size_t)b * NT + (actD ? tD : 0)];
    float4 kA[4], kB[4], kC[4], kD[4];
    {
        const float4* rpA = (const float4*)(item_table + (size_t)hrA * NE) + quarter * 4;
        const float4* rpB = (const float4*)(item_table + (size_t)hrB * NE) + quarter * 4;
        const float4* rpC = (const float4*)(item_table + (size_t)hrC * NE) + quarter * 4;
        const float4* rpD = (const float4*)(item_table + (size_t)hrD * NE) + quarter * 4;
#pragma unroll
        for (int i = 0; i < 4; ++i) {
            kA[i] = rpA[i]; kB[i] = rpB[i]; kC[i] = rpC[i]; kD[i] = rpD[i];
        }
    }

    // ---- stage small shared data ----------------------------------------
    if (tid < NE) sm.q[tid] = item_table[(size_t)target_item[b] * NE + tid];
    for (int i = tid; i < 512; i += 256)
        ((float4*)sm.w2)[i] = ((const float4*)att_w2)[i];
    if (tid < 32) { sm.b2[tid] = att_b2[tid]; sm.wo[tid] = att_wo[tid]; }
    const float bo = att_bo[0];
    __syncthreads();

    // ---- W_eff^T[j][e] + bias partials (thread = (wv, j), 16 e's) -------
    // attn_in = [k, q, k-q, k*q] @ w1 factorizes (q row-constant):
    // h1[j] = relu( sum_e k_e*(w1[e,j]+w1[128+e,j]+q_e*w1[192+e,j])
    //              + b1[j] + sum_e q_e*(w1[64+e,j]-w1[128+e,j]) )
    {
        float pb = 0.f;
        for (int e = wv; e < NE; e += 4) {
            const float qe = sm.q[e];
            const float A  = att_w1[(size_t)(e)       * NE + j];
            const float Bv = att_w1[(size_t)(64 + e)  * NE + j];
            const float C  = att_w1[(size_t)(128 + e) * NE + j];
            const float D  = att_w1[(size_t)(192 + e) * NE + j];
            sm.weffT[j * 72 + e] = A + C + qe * D;
            pb += qe * (Bv - C);
        }
        sm.ip[wv * 64 + j] = pb;
    }
    __syncthreads();
    if (tid < NE)
        sm.biasj[tid] = att_b1[tid] + sm.ip[tid] + sm.ip[64 + tid] +
                        sm.ip[128 + tid] + sm.ip[192 + tid];
    __syncthreads();

    // ---- main loop: lane does its e-quarter of FOUR t's -----------------
    float h2A[8], h2B[8], h2C[8], h2D[8];
#pragma unroll
    for (int o = 0; o < 8; ++o) { h2A[o] = 0.f; h2B[o] = 0.f; h2C[o] = 0.f; h2D[o] = 0.f; }

    for (int jj = 0; jj < 64; ++jj) {
        const float4* wrow =
            (const float4*)(sm.weffT + jj * 72) + quarter * 4;   // own quarter
        float aA = 0.f, aB = 0.f, aC = 0.f, aD = 0.f;
#pragma unroll
        for (int i = 0; i < 4; ++i) {
            const float4 w = wrow[i];
            aA += w.x * kA[i].x; aB += w.x * kB[i].x;
            aC += w.x * kC[i].x; aD += w.x * kD[i].x;
            aA += w.y * kA[i].y; aB += w.y * kB[i].y;
            aC += w.y * kC[i].y; aD += w.y * kD[i].y;
            aA += w.z * kA[i].z; aB += w.z * kB[i].z;
            aC += w.z * kC[i].z; aD += w.z * kD[i].z;
            aA += w.w * kA[i].w; aB += w.w * kB[i].w;
            aC += w.w * kC[i].w; aD += w.w * kD[i].w;
        }
        // combine quarters within the quad (quad-perm DPP, VALU pipe)
        aA += dpp_xor1(aA); aA += dpp_xor2(aA);
        aB += dpp_xor1(aB); aB += dpp_xor2(aB);
        aC += dpp_xor1(aC); aC += dpp_xor2(aC);
        aD += dpp_xor1(aD); aD += dpp_xor2(aD);
        const float bias = sm.biasj[jj];
        const float h1A = fmaxf(aA + bias, 0.f);
        const float h1B = fmaxf(aB + bias, 0.f);
        const float h1C = fmaxf(aC + bias, 0.f);
        const float h1D = fmaxf(aD + bias, 0.f);

        const float4* w2q =
            (const float4*)(sm.w2 + jj * 32) + quarter * 2;      // own quarter
        const float4 u0 = w2q[0];
        const float4 u1 = w2q[1];
        h2A[0] += h1A * u0.x; h2B[0] += h1B * u0.x; h2C[0] += h1C * u0.x; h2D[0] += h1D * u0.x;
        h2A[1] += h1A * u0.y; h2B[1] += h1B * u0.y; h2C[1] += h1C * u0.y; h2D[1] += h1D * u0.y;
        h2A[2] += h1A * u0.z; h2B[2] += h1B * u0.z; h2C[2] += h1C * u0.z; h2D[2] += h1D * u0.z;
        h2A[3] += h1A * u0.w; h2B[3] += h1B * u0.w; h2C[3] += h1C * u0.w; h2D[3] += h1D * u0.w;
        h2A[4] += h1A * u1.x; h2B[4] += h1B * u1.x; h2C[4] += h1C * u1.x; h2D[4] += h1D * u1.x;
        h2A[5] += h1A * u1.y; h2B[5] += h1B * u1.y; h2C[5] += h1C * u1.y; h2D[5] += h1D * u1.y;
        h2A[6] += h1A * u1.z; h2B[6] += h1B * u1.z; h2C[6] += h1C * u1.z; h2D[6] += h1D * u1.z;
        h2A[7] += h1A * u1.w; h2B[7] += h1B * u1.w; h2C[7] += h1C * u1.w; h2D[7] += h1D * u1.w;
    }

    // ---- L3 scores (own 8-o quarter, then quad-combine) -----------------
    float sA = 0.f, sB = 0.f, sC = 0.f, sD = 0.f;
#pragma unroll
    for (int o = 0; o < 8; ++o) {
        const float bb  = sm.b2[quarter * 8 + o];
        const float wwo = sm.wo[quarter * 8 + o];
        sA += fmaxf(h2A[o] + bb, 0.f) * wwo;
        sB += fmaxf(h2B[o] + bb, 0.f) * wwo;
        sC += fmaxf(h2C[o] + bb, 0.f) * wwo;
        sD += fmaxf(h2D[o] + bb, 0.f) * wwo;
    }
    sA += dpp_xor1(sA); sA += dpp_xor2(sA);
    sB += dpp_xor1(sB); sB += dpp_xor2(sB);
    sC += dpp_xor1(sC); sC += dpp_xor2(sC);
    sD += dpp_xor1(sD); sD += dpp_xor2(sD);
    const float scrA = sA + bo;
    const float scrB = sB + bo;
    const float scrC = sC + bo;
    const float scrD = sD + bo;
    const int mkA = history_mask[(size_t)b * NT + tA];
    const int mkB = history_mask[(size_t)b * NT + tB];
    const int mkC = history_mask[(size_t)b * NT + tC];
    const int mkD = actD ? history_mask[(size_t)b * NT + tD] : 0;
    const float vA = (mkA != 0) ? scrA : -1e9f;
    const float vB = (mkB != 0) ? scrB : -1e9f;
    const float vC = (mkC != 0) ? scrC : -1e9f;
    const float vD = actD ? ((mkD != 0) ? scrD : -1e9f) : -INFINITY;
    // lane's quarter selects which t it represents -> 256 slots, each once
    const float v = (quarter == 0) ? vA : (quarter == 1) ? vB
                  : (quarter == 2) ? vC : vD;

    // ---- softmax over 256 slots (4-wave reduce) -------------------------
    float m = v;
#pragma unroll
    for (int s = 32; s; s >>= 1) m = fmaxf(m, __shfl_xor(m, s));
    if (j == 0) sm.red_a[wv] = m;
    __syncthreads();
    const float mx = fmaxf(fmaxf(sm.red_a[0], sm.red_a[1]),
                           fmaxf(sm.red_a[2], sm.red_a[3]));
    const float ex = __expf(v - mx);   // -inf -> 0
    float ssum = ex;
#pragma unroll
    for (int s = 32; s; s >>= 1) ssum += __shfl_xor(ssum, s);
    if (j == 0) sm.red_b[wv] = ssum;
    __syncthreads();
    const float total = sm.red_b[0] + sm.red_b[1] + sm.red_b[2] + sm.red_b[3];
    const float w = ex / total;
    // redistribute all four t-weights to every lane of the quad (DPP bcast)
    const float wA = dpp_b0(w);
    const float wB = dpp_b1(w);
    const float wC = dpp_b2(w);
    const float wD = dpp_b3(w);

    // ---- interest: own e-quarter of 4 t's, butterfly over 16 groups -----
#pragma unroll
    for (int i = 0; i < 16; ++i)
        C4(kA, i) = C4(kA, i) * wA + C4(kB, i) * wB +
                    C4(kC, i) * wC + C4(kD, i) * wD;
    BFQ(8)
    BFQ(4)
    BFQ(2)
    BFQ(1)
    // lane now holds this wave's partial interest for e = quarter*16 + g
    sm.ip[wv * 64 + quarter * 16 + g] = kA[0].x;
    __syncthreads();

    // ---- assemble mlp_in row [user, ctx, q, interest, dense] ------------
    float* row = mlp_in + (size_t)b * 272;
    if (tid < NE) {
        const float inter = sm.ip[tid] + sm.ip[64 + tid] +
                            sm.ip[128 + tid] + sm.ip[192 + tid];
        row[0 + tid]   = user_table[(size_t)sparse_features[b * 2 + 0] * NE + tid];
        row[64 + tid]  = ctx_table[(size_t)sparse_features[b * 2 + 1] * NE + tid];
        row[128 + tid] = sm.q[tid];
        row[192 + tid] = inter;
    } else if (tid >= 64 && tid < 80) {
        row[256 + (tid - 64)] = dense_features[(size_t)b * 16 + (tid - 64)];
    }
}

// ---------------------------------------------------------------------------
// Kernel 2: final MLP 272 -> 256 -> 128 -> 1, 4 rows/block (grid 1024,
// 4 blocks/CU) with transposed LDS activations (broadcast b128 reads) and
// unroll-8 load pipelining.
// ---------------------------------------------------------------------------
#define MR 4
__global__ __launch_bounds__(256)
void din_mlp(const float* __restrict__ mlp_in,
             const float* __restrict__ w1,
             const float* __restrict__ b1,
             const float* __restrict__ w2,
             const float* __restrict__ b2,
             const float* __restrict__ ow,
             const float* __restrict__ ob,
             float* __restrict__ out)
{
    __shared__ float inT[272 * MR];     // [k][r]
    __shared__ float h1T[256 * MR];     // [k][r]
    __shared__ float p2[2 * MR * 128];
    __shared__ float h2_lds[MR * 128];

    const int b0  = blockIdx.x * MR;
    const int tid = threadIdx.x;

    // stage transposed: coalesced global read, scattered LDS write
    for (int i = tid; i < MR * 272; i += 256) {
        const int r = i / 272, k = i - 272 * r;
        inT[k * MR + r] = mlp_in[(size_t)b0 * 272 + i];
    }
    __syncthreads();

    // layer 1: 272 -> 256 (thread = col, MR rows via 1 b128 broadcast/k)
    {
        const float bias = b1[tid];
        float a0 = bias, a1 = bias, a2 = bias, a3 = bias;
        const float4* iT = (const float4*)inT;
#pragma unroll 8
        for (int k = 0; k < 272; ++k) {
            const float wv = w1[(size_t)k * 256 + tid];
            const float4 iv = iT[k];
            a0 += iv.x * wv; a1 += iv.y * wv;
            a2 += iv.z * wv; a3 += iv.w * wv;
        }
        float4 o;
        o.x = fmaxf(a0, 0.f); o.y = fmaxf(a1, 0.f);
        o.z = fmaxf(a2, 0.f); o.w = fmaxf(a3, 0.f);
        ((float4*)h1T)[tid] = o;        // h1T[k=tid][r] contiguous
    }
    __syncthreads();

    // layer 2: 256 -> 128, split-K over two half-blocks
    {
        const int o = tid & 127, half = tid >> 7;
        float c0 = 0.f, c1 = 0.f, c2 = 0.f, c3 = 0.f;
        const float4* hT = (const float4*)h1T;
#pragma unroll 8
        for (int kk = 0; kk < 128; ++kk) {
            const int k = half * 128 + kk;
            const float wv = w2[(size_t)k * 128 + o];
            const float4 hv = hT[k];
            c0 += hv.x * wv; c1 += hv.y * wv;
            c2 += hv.z * wv; c3 += hv.w * wv;
        }
        p2[(half * MR + 0) * 128 + o] = c0;
        p2[(half * MR + 1) * 128 + o] = c1;
        p2[(half * MR + 2) * 128 + o] = c2;
        p2[(half * MR + 3) * 128 + o] = c3;
    }
    __syncthreads();
    if (tid < 128) {
        const float bias = b2[tid];
#pragma unroll
        for (int r = 0; r < MR; ++r)
            h2_lds[r * 128 + tid] =
                fmaxf(p2[r * 128 + tid] + p2[(MR + r) * 128 + tid] + bias, 0.f);
    }
    __syncthreads();

    // layer 3: 128 -> 1 (16 lanes per row)
    if (tid < 16 * MR) {
        const int r = tid >> 4, l = tid & 15;
        float a = 0.f;
#pragma unroll
        for (int kk = 0; kk < 8; ++kk) {
            const int k = l * 8 + kk;
            a += h2_lds[r * 128 + k] * ow[k];
        }
        a += __shfl_xor(a, 8, 16);
        a += __shfl_xor(a, 4, 16);
        a += __shfl_xor(a, 2, 16);
        a += __shfl_xor(a, 1, 16);
        if (l == 0) out[b0 + r] = a + ob[0];
    }
}

// ---------------------------------------------------------------------------
extern "C" void kernel_launch(void* const* d_in, const int* in_sizes, int n_in,
                              void* d_out, int out_size, void* d_ws, size_t ws_size,
                              hipStream_t stream)
{
    float* mlp_in = (float*)d_ws;   // 4096*272*4 = 4.46 MB

    din_attn<<<NB, 256, 0, stream>>>(
        (const int*)d_in[0],      // target_item
        (const int*)d_in[1],      // history_items
        (const int*)d_in[2],      // history_mask
        (const int*)d_in[3],      // sparse_features
        (const float*)d_in[4],    // dense_features
        (const float*)d_in[5],    // item_table
        (const float*)d_in[6],    // user_table
        (const float*)d_in[7],    // ctx_table
        (const float*)d_in[8],  (const float*)d_in[9],   // att_w1, att_b1
        (const float*)d_in[10], (const float*)d_in[11],  // att_w2, att_b2
        (const float*)d_in[12], (const float*)d_in[13],  // att_wo, att_bo
        mlp_in);

    din_mlp<<<NB / MR, 256, 0, stream>>>(
        mlp_in,
        (const float*)d_in[14], (const float*)d_in[15],  // mlp_w1, mlp_b1
        (const float*)d_in[16], (const float*)d_in[17],  // mlp_w2, mlp_b2
        (const float*)d_in[18], (const float*)d_in[19],  // out_w, out_b
        (float*)d_out);
}

// Round 11
// 314.969 us; speedup vs baseline: 1.8747x; 1.1108x over previous
//
#include <hip/hip_runtime.h>
#include <stdint.h>

#define NB 4096
#define NT 200
#define NE 64
// attention: 4E=256 -> 64 -> 32 -> 1 ; final MLP: 272 -> 256 -> 128 -> 1
//
// ABI (proven R2-R10): identity order, fp32 floats, int32 ints, FP32 output.
//
// R24: MFMA attention (bf16 split hi/lo, 3-term) -- use the idle matrix pipe.
//  - 11-round ledger: VALU formulation is pinned at ~94% VALUBusy and
//    ~204-237us VALU-time (2.3x the 95us FMA floor); no allocator knob
//    (launch_bounds N, waves_per_eu) breaks it. MfmaUtil = 0.0 always.
//  - L1/L2 are per-batch GEMMs: (256x64)x(64x64), (256x64)x(64x32).
//    bf16 split: x = hi + lo; x*w ~ hi*wh + hi*wl + lo*wh (3 MFMAs,
//    rel err ~2^-16). MFMA 144/wave ~ 5us; VALU drops ~3.5x.
//  - Layouts: A/B frag: row/col = lane&15, k = (lane>>4)*8+i (k-perm
//    errors cancel between A and B); C/D: col=lane&15,
//    row=(lane>>4)*4+r (m89-verified). C1->A2 transpose via wave-private
//    LDS bounce (DS ops in-order within a wave; no barrier).
//  - M padded to 256 rows (wave w owns tiles 4w..4w+3); dead rows get
//    -INF scores; masked real rows get -1e9 (reference parity).
//  - Interest recomputed in FP32 (gather K rows again, L2-hot), so bf16
//    never directly feeds the output path.
//  - din_mlp: unchanged (MR=4, transposed LDS, unroll-8).

typedef __attribute__((ext_vector_type(8))) __bf16 bf16x8;
typedef __attribute__((ext_vector_type(4))) float f32x4;

__device__ __forceinline__ void cvt8(const float4 a, const float4 b,
                                     bf16x8& hi, bf16x8& lo)
{
    float x[8] = {a.x, a.y, a.z, a.w, b.x, b.y, b.z, b.w};
#pragma unroll
    for (int i = 0; i < 8; ++i) {
        const __bf16 h = (__bf16)x[i];
        hi[i] = h;
        lo[i] = (__bf16)(x[i] - (float)h);
    }
}

struct __align__(16) SmemM {
    __bf16 wT_hi[64 * 72];    // WeffT[j][k], pitch 72 (144B, b128-aligned)
    __bf16 wT_lo[64 * 72];
    __bf16 w2T_hi[32 * 72];   // w2T[o][j]
    __bf16 w2T_lo[32 * 72];
    float  q[64];
    float  biasj[64];
    float  b2[32];
    float  wo[32];
    float  ip[4 * 64];        // bias partials, later interest partials
    float  red_a[4];
    float  red_b[4];
    float  scores[256];
    float  bounce[4][16 * 36];  // per-wave transpose buffer (pitch 36 dw)
};                               // ~39.7 KB -> 4 blocks/CU by LDS

__global__ __launch_bounds__(256)
void din_attn(const int* __restrict__ target_item,
              const int* __restrict__ history_items,
              const int* __restrict__ history_mask,
              const int* __restrict__ sparse_features,
              const float* __restrict__ dense_features,
              const float* __restrict__ item_table,
              const float* __restrict__ user_table,
              const float* __restrict__ ctx_table,
              const float* __restrict__ att_w1,
              const float* __restrict__ att_b1,
              const float* __restrict__ att_w2,
              const float* __restrict__ att_b2,
              const float* __restrict__ att_wo,
              const float* __restrict__ att_bo,
              float* __restrict__ mlp_in)   // [NB][272]
{
    __shared__ SmemM sm;

    const int b    = blockIdx.x;
    const int tid  = threadIdx.x;    // 0..255
    const int wv   = tid >> 6;       // wave 0..3
    const int lane = tid & 63;
    const int l15  = lane & 15;
    const int g4   = lane >> 4;      // 0..3

    // ---- A-fragments: gather own key rows, split to bf16 hi/lo ----------
    // A[row][k]: row = 64*wv + mt*16 + (lane&15), k = ks*32 + (lane>>4)*8+i
    bf16x8 khi[4][2], klo[4][2];
#pragma unroll
    for (int mt = 0; mt < 4; ++mt) {
        int t = 64 * wv + mt * 16 + l15;
        if (t > NT - 1) t = NT - 1;                 // dead rows: masked later
        const int hr = history_items[(size_t)b * NT + t];
        const float* kp = item_table + (size_t)hr * NE + g4 * 8;
#pragma unroll
        for (int ks = 0; ks < 2; ++ks) {
            const float4 f0 = *(const float4*)(kp + ks * 32);
            const float4 f1 = *(const float4*)(kp + ks * 32 + 4);
            cvt8(f0, f1, khi[mt][ks], klo[mt][ks]);
        }
    }

    // ---- stage q, b2, wo -------------------------------------------------
    if (tid < NE) sm.q[tid] = item_table[(size_t)target_item[b] * NE + tid];
    if (tid < 32) { sm.b2[tid] = att_b2[tid]; sm.wo[tid] = att_wo[tid]; }
    const float bo = att_bo[0];
    __syncthreads();

    // ---- Weff^T split staging + bias partials ---------------------------
    // h1[j] = relu( sum_e k_e*(A+C+q_e*D)[e][j] + b1[j] + sum_e q_e*(B-C)[e][j] )
    {
        const int j = tid & 63;
        float pb = 0.f;
        for (int e = wv; e < NE; e += 4) {
            const float qe = sm.q[e];
            const float A  = att_w1[(size_t)(e)       * NE + j];
            const float Bv = att_w1[(size_t)(64 + e)  * NE + j];
            const float C  = att_w1[(size_t)(128 + e) * NE + j];
            const float D  = att_w1[(size_t)(192 + e) * NE + j];
            const float wf = A + C + qe * D;
            const __bf16 hi = (__bf16)wf;
            sm.wT_hi[j * 72 + e] = hi;
            sm.wT_lo[j * 72 + e] = (__bf16)(wf - (float)hi);
            pb += qe * (Bv - C);
        }
        sm.ip[wv * 64 + j] = pb;
    }
    // w2T[o][j] split staging (32x64, 8 elems/thread)
    {
        const int o  = tid & 31;
        const int jb = (tid >> 5) * 8;
#pragma unroll
        for (int i = 0; i < 8; ++i) {
            const int j = jb + i;
            const float v = att_w2[(size_t)j * 32 + o];
            const __bf16 hi = (__bf16)v;
            sm.w2T_hi[o * 72 + j] = hi;
            sm.w2T_lo[o * 72 + j] = (__bf16)(v - (float)hi);
        }
    }
    __syncthreads();
    if (tid < NE)
        sm.biasj[tid] = att_b1[tid] + sm.ip[tid] + sm.ip[64 + tid] +
                        sm.ip[128 + tid] + sm.ip[192 + tid];
    __syncthreads();

    // ---- L1 GEMM: h1[256x64] = K[256x64] . Weff[64x64]  (split, 96 MFMA) -
    f32x4 acc1[4][4];
    {
        const f32x4 z = {0.f, 0.f, 0.f, 0.f};
#pragma unroll
        for (int mt = 0; mt < 4; ++mt)
#pragma unroll
            for (int nt = 0; nt < 4; ++nt) acc1[mt][nt] = z;
    }
#pragma unroll
    for (int nt = 0; nt < 4; ++nt) {
        const __bf16* bph = sm.wT_hi + (nt * 16 + l15) * 72 + g4 * 8;
        const __bf16* bpl = sm.wT_lo + (nt * 16 + l15) * 72 + g4 * 8;
        const bf16x8 bh0 = *(const bf16x8*)(bph);
        const bf16x8 bh1 = *(const bf16x8*)(bph + 32);
        const bf16x8 bl0 = *(const bf16x8*)(bpl);
        const bf16x8 bl1 = *(const bf16x8*)(bpl + 32);
#pragma unroll
        for (int mt = 0; mt < 4; ++mt) {
            f32x4 a = acc1[mt][nt];
            a = __builtin_amdgcn_mfma_f32_16x16x32_bf16(khi[mt][0], bh0, a, 0, 0, 0);
            a = __builtin_amdgcn_mfma_f32_16x16x32_bf16(khi[mt][0], bl0, a, 0, 0, 0);
            a = __builtin_amdgcn_mfma_f32_16x16x32_bf16(klo[mt][0], bh0, a, 0, 0, 0);
            a = __builtin_amdgcn_mfma_f32_16x16x32_bf16(khi[mt][1], bh1, a, 0, 0, 0);
            a = __builtin_amdgcn_mfma_f32_16x16x32_bf16(khi[mt][1], bl1, a, 0, 0, 0);
            a = __builtin_amdgcn_mfma_f32_16x16x32_bf16(klo[mt][1], bh1, a, 0, 0, 0);
            acc1[mt][nt] = a;
        }
    }

    // ---- bias + ReLU on C1 (col = nt*16+l15, row = mt*16+g4*4+r) --------
#pragma unroll
    for (int nt = 0; nt < 4; ++nt) {
        const float bj = sm.biasj[nt * 16 + l15];
#pragma unroll
        for (int mt = 0; mt < 4; ++mt)
#pragma unroll
            for (int r = 0; r < 4; ++r)
                acc1[mt][nt][r] = fmaxf(acc1[mt][nt][r] + bj, 0.f);
    }

    // ---- transpose C1-layout -> A2-fragments via wave-private bounce ----
    bf16x8 a2hi[4][2], a2lo[4][2];
    {
        float* bnc = sm.bounce[wv];
#pragma unroll
        for (int mt = 0; mt < 4; ++mt) {
#pragma unroll
            for (int k2s = 0; k2s < 2; ++k2s) {
#pragma unroll
                for (int ntl = 0; ntl < 2; ++ntl) {
                    const int nt = k2s * 2 + ntl;
#pragma unroll
                    for (int r = 0; r < 4; ++r)
                        bnc[(g4 * 4 + r) * 36 + ntl * 16 + l15] = acc1[mt][nt][r];
                }
                // same-wave DS ops are ordered; compiler inserts lgkm waits
                const float* rp = bnc + l15 * 36 + g4 * 8;
                const float4 u0 = *(const float4*)(rp);
                const float4 u1 = *(const float4*)(rp + 4);
                cvt8(u0, u1, a2hi[mt][k2s], a2lo[mt][k2s]);
            }
        }
    }

    // ---- L2 GEMM: h2[256x32] = h1 . W2 (split, 48 MFMA) -----------------
    f32x4 acc2[4][2];
    {
        const f32x4 z = {0.f, 0.f, 0.f, 0.f};
#pragma unroll
        for (int mt = 0; mt < 4; ++mt) { acc2[mt][0] = z; acc2[mt][1] = z; }
    }
#pragma unroll
    for (int nt2 = 0; nt2 < 2; ++nt2) {
        const __bf16* bph = sm.w2T_hi + (nt2 * 16 + l15) * 72 + g4 * 8;
        const __bf16* bpl = sm.w2T_lo + (nt2 * 16 + l15) * 72 + g4 * 8;
        const bf16x8 bh0 = *(const bf16x8*)(bph);
        const bf16x8 bh1 = *(const bf16x8*)(bph + 32);
        const bf16x8 bl0 = *(const bf16x8*)(bpl);
        const bf16x8 bl1 = *(const bf16x8*)(bpl + 32);
#pragma unroll
        for (int mt = 0; mt < 4; ++mt) {
            f32x4 a = acc2[mt][nt2];
            a = __builtin_amdgcn_mfma_f32_16x16x32_bf16(a2hi[mt][0], bh0, a, 0, 0, 0);
            a = __builtin_amdgcn_mfma_f32_16x16x32_bf16(a2hi[mt][0], bl0, a, 0, 0, 0);
            a = __builtin_amdgcn_mfma_f32_16x16x32_bf16(a2lo[mt][0], bh0, a, 0, 0, 0);
            a = __builtin_amdgcn_mfma_f32_16x16x32_bf16(a2hi[mt][1], bh1, a, 0, 0, 0);
            a = __builtin_amdgcn_mfma_f32_16x16x32_bf16(a2hi[mt][1], bl1, a, 0, 0, 0);
            a = __builtin_amdgcn_mfma_f32_16x16x32_bf16(a2lo[mt][1], bh1, a, 0, 0, 0);
            acc2[mt][nt2] = a;
        }
    }

    // ---- L3 scores: relu(h2+b2).wo, reduce over the 16 col-lanes --------
    float sc[4][4];
#pragma unroll
    for (int mt = 0; mt < 4; ++mt)
#pragma unroll
        for (int r = 0; r < 4; ++r) sc[mt][r] = 0.f;
#pragma unroll
    for (int nt2 = 0; nt2 < 2; ++nt2) {
        const float bb = sm.b2[nt2 * 16 + l15];
        const float ww = sm.wo[nt2 * 16 + l15];
#pragma unroll
        for (int mt = 0; mt < 4; ++mt)
#pragma unroll
            for (int r = 0; r < 4; ++r)
                sc[mt][r] += fmaxf(acc2[mt][nt2][r] + bb, 0.f) * ww;
    }
#pragma unroll
    for (int mt = 0; mt < 4; ++mt)
#pragma unroll
        for (int r = 0; r < 4; ++r) {
            float v = sc[mt][r];
            v += __shfl_xor(v, 1);
            v += __shfl_xor(v, 2);
            v += __shfl_xor(v, 4);
            v += __shfl_xor(v, 8);
            sc[mt][r] = v;
        }
    if (l15 == 0) {
#pragma unroll
        for (int mt = 0; mt < 4; ++mt)
#pragma unroll
            for (int r = 0; r < 4; ++r) {
                const int t = 64 * wv + mt * 16 + g4 * 4 + r;
                float val;
                if (t < NT) {
                    const int mk = history_mask[(size_t)b * NT + t];
                    val = (mk != 0) ? (sc[mt][r] + bo) : -1e9f;
                } else {
                    val = -INFINITY;       // pad rows excluded from softmax
                }
                sm.scores[t] = val;
            }
    }
    __syncthreads();

    // ---- softmax over 256 slots (4-wave reduce) -------------------------
    const float v = sm.scores[tid];
    float m = v;
#pragma unroll
    for (int s = 32; s; s >>= 1) m = fmaxf(m, __shfl_xor(m, s));
    if (lane == 0) sm.red_a[wv] = m;
    __syncthreads();
    const float mx = fmaxf(fmaxf(sm.red_a[0], sm.red_a[1]),
                           fmaxf(sm.red_a[2], sm.red_a[3]));
    const float ex = __expf(v - mx);   // -inf -> 0
    float ssum = ex;
#pragma unroll
    for (int s = 32; s; s >>= 1) ssum += __shfl_xor(ssum, s);
    if (lane == 0) sm.red_b[wv] = ssum;
    __syncthreads();
    const float total = sm.red_b[0] + sm.red_b[1] + sm.red_b[2] + sm.red_b[3];
    sm.scores[tid] = ex / total;       // softmax weight of slot tid
    __syncthreads();

    // ---- interest in FP32: re-gather K rows (L2/L3-hot), weighted sum ---
    {
        const int e = lane;            // 0..63
        float acc = 0.f;
        const int tb = (NT / 4) * wv;  // 50 per wave, exact
#pragma unroll 2
        for (int i = 0; i < NT / 4; ++i) {
            const int t = tb + i;
            const float wt = sm.scores[t];
            const int hr = history_items[(size_t)b * NT + t];
            acc += wt * item_table[(size_t)hr * NE + e];
        }
        sm.ip[wv * 64 + e] = acc;
    }
    __syncthreads();

    // ---- assemble mlp_in row [user, ctx, q, interest, dense] ------------
    float* row = mlp_in + (size_t)b * 272;
    if (tid < NE) {
        const float inter = sm.ip[tid] + sm.ip[64 + tid] +
                            sm.ip[128 + tid] + sm.ip[192 + tid];
        row[0 + tid]   = user_table[(size_t)sparse_features[b * 2 + 0] * NE + tid];
        row[64 + tid]  = ctx_table[(size_t)sparse_features[b * 2 + 1] * NE + tid];
        row[128 + tid] = sm.q[tid];
        row[192 + tid] = inter;
    } else if (tid >= 64 && tid < 80) {
        row[256 + (tid - 64)] = dense_features[(size_t)b * 16 + (tid - 64)];
    }
}

// ---------------------------------------------------------------------------
// Kernel 2: final MLP 272 -> 256 -> 128 -> 1, 4 rows/block (grid 1024,
// 4 blocks/CU) with transposed LDS activations (broadcast b128 reads) and
// unroll-8 load pipelining.  (unchanged from R23)
// ---------------------------------------------------------------------------
#define MR 4
__global__ __launch_bounds__(256)
void din_mlp(const float* __restrict__ mlp_in,
             const float* __restrict__ w1,
             const float* __restrict__ b1,
             const float* __restrict__ w2,
             const float* __restrict__ b2,
             const float* __restrict__ ow,
             const float* __restrict__ ob,
             float* __restrict__ out)
{
    __shared__ float inT[272 * MR];     // [k][r]
    __shared__ float h1T[256 * MR];     // [k][r]
    __shared__ float p2[2 * MR * 128];
    __shared__ float h2_lds[MR * 128];

    const int b0  = blockIdx.x * MR;
    const int tid = threadIdx.x;

    // stage transposed: coalesced global read, scattered LDS write
    for (int i = tid; i < MR * 272; i += 256) {
        const int r = i / 272, k = i - 272 * r;
        inT[k * MR + r] = mlp_in[(size_t)b0 * 272 + i];
    }
    __syncthreads();

    // layer 1: 272 -> 256 (thread = col, MR rows via 1 b128 broadcast/k)
    {
        const float bias = b1[tid];
        float a0 = bias, a1 = bias, a2 = bias, a3 = bias;
        const float4* iT = (const float4*)inT;
#pragma unroll 8
        for (int k = 0; k < 272; ++k) {
            const float wv = w1[(size_t)k * 256 + tid];
            const float4 iv = iT[k];
            a0 += iv.x * wv; a1 += iv.y * wv;
            a2 += iv.z * wv; a3 += iv.w * wv;
        }
        float4 o;
        o.x = fmaxf(a0, 0.f); o.y = fmaxf(a1, 0.f);
        o.z = fmaxf(a2, 0.f); o.w = fmaxf(a3, 0.f);
        ((float4*)h1T)[tid] = o;        // h1T[k=tid][r] contiguous
    }
    __syncthreads();

    // layer 2: 256 -> 128, split-K over two half-blocks
    {
        const int o = tid & 127, half = tid >> 7;
        float c0 = 0.f, c1 = 0.f, c2 = 0.f, c3 = 0.f;
        const float4* hT = (const float4*)h1T;
#pragma unroll 8
        for (int kk = 0; kk < 128; ++kk) {
            const int k = half * 128 + kk;
            const float wv = w2[(size_t)k * 128 + o];
            const float4 hv = hT[k];
            c0 += hv.x * wv; c1 += hv.y * wv;
            c2 += hv.z * wv; c3 += hv.w * wv;
        }
        p2[(half * MR + 0) * 128 + o] = c0;
        p2[(half * MR + 1) * 128 + o] = c1;
        p2[(half * MR + 2) * 128 + o] = c2;
        p2[(half * MR + 3) * 128 + o] = c3;
    }
    __syncthreads();
    if (tid < 128) {
        const float bias = b2[tid];
#pragma unroll
        for (int r = 0; r < MR; ++r)
            h2_lds[r * 128 + tid] =
                fmaxf(p2[r * 128 + tid] + p2[(MR + r) * 128 + tid] + bias, 0.f);
    }
    __syncthreads();

    // layer 3: 128 -> 1 (16 lanes per row)
    if (tid < 16 * MR) {
        const int r = tid >> 4, l = tid & 15;
        float a = 0.f;
#pragma unroll
        for (int kk = 0; kk < 8; ++kk) {
            const int k = l * 8 + kk;
            a += h2_lds[r * 128 + k] * ow[k];
        }
        a += __shfl_xor(a, 8, 16);
        a += __shfl_xor(a, 4, 16);
        a += __shfl_xor(a, 2, 16);
        a += __shfl_xor(a, 1, 16);
        if (l == 0) out[b0 + r] = a + ob[0];
    }
}

// ---------------------------------------------------------------------------
extern "C" void kernel_launch(void* const* d_in, const int* in_sizes, int n_in,
                              void* d_out, int out_size, void* d_ws, size_t ws_size,
                              hipStream_t stream)
{
    float* mlp_in = (float*)d_ws;   // 4096*272*4 = 4.46 MB

    din_attn<<<NB, 256, 0, stream>>>(
        (const int*)d_in[0],      // target_item
        (const int*)d_in[1],      // history_items
        (const int*)d_in[2],      // history_mask
        (const int*)d_in[3],      // sparse_features
        (const float*)d_in[4],    // dense_features
        (const float*)d_in[5],    // item_table
        (const float*)d_in[6],    // user_table
        (const float*)d_in[7],    // ctx_table
        (const float*)d_in[8],  (const float*)d_in[9],   // att_w1, att_b1
        (const float*)d_in[10], (const float*)d_in[11],  // att_w2, att_b2
        (const float*)d_in[12], (const float*)d_in[13],  // att_wo, att_bo
        mlp_in);

    din_mlp<<<NB / MR, 256, 0, stream>>>(
        mlp_in,
        (const float*)d_in[14], (const float*)d_in[15],  // mlp_w1, mlp_b1
        (const float*)d_in[16], (const float*)d_in[17],  // mlp_w2, mlp_b2
        (const float*)d_in[18], (const float*)d_in[19],  // out_w, out_b
        (float*)d_out);
}